// Round 9
// baseline (4495.565 us; speedup 1.0000x reference)
//
#include <hip/hip_runtime.h>
#include <hip/hip_bf16.h>

#define B_ 512
#define T_ 128
#define DIN_ 256
#define H_ 512
#define KP_ 520             // LDS stride (bf16) K=512 weights
#define KP0_ 264            // LDS stride K=256 (wih0)
#define OUT_MAIN ((size_t)B_ * T_ * H_)

// ws byte offsets
#define OFF_H1  2097152ull   // h1 ring (h0 ring at 0)
#define OFF_W1  4194304ull   // bf16 wih1 (1.5 MB)
#define OFF_FLG 8388608ull   // flags

typedef __attribute__((ext_vector_type(8))) short short8;
typedef __attribute__((ext_vector_type(4))) float f32x4;

__device__ __forceinline__ float sigm(float v) { return 1.0f / (1.0f + __expf(-v)); }

__device__ __forceinline__ unsigned short f2bf(float f) {
    union { __hip_bfloat16 b; unsigned short u; } c;
    c.b = __float2bfloat16(f);
    return c.u;
}

__device__ __forceinline__ short8 cvt8v(f32x4 u, f32x4 v) {
    short8 o;
    o[0] = (short)f2bf(u[0]); o[1] = (short)f2bf(u[1]);
    o[2] = (short)f2bf(u[2]); o[3] = (short)f2bf(u[3]);
    o[4] = (short)f2bf(v[0]); o[5] = (short)f2bf(v[1]);
    o[6] = (short)f2bf(v[2]); o[7] = (short)f2bf(v[3]);
    return o;
}

// 16B coherent-point load (bypass L1/L2 on all XCDs)
__device__ __forceinline__ short8 ld16sc(const __hip_bfloat16* p) {
    short8 r;
    asm volatile("global_load_dwordx4 %0, %1, off sc0 sc1" : "=v"(r) : "v"(p));
    return r;
}
#define VMWAIT(N) do { asm volatile("s_waitcnt vmcnt(" #N ")" ::: "memory"); \
                       __builtin_amdgcn_sched_barrier(0); } while (0)

__device__ __forceinline__ void st8sc(__hip_bfloat16* p, unsigned long long v) {
    __hip_atomic_store((unsigned long long*)p, v, __ATOMIC_RELAXED, __HIP_MEMORY_SCOPE_AGENT);
}

__global__ void prep_kernel(const float* __restrict__ wih1,
                            __hip_bfloat16* __restrict__ bw1,
                            int* __restrict__ flg)
{
    int tid = blockIdx.x * blockDim.x + threadIdx.x;
    int stride = gridDim.x * blockDim.x;
    for (int i = tid; i < 16384; i += stride) flg[i] = 0;
    for (int i = tid; i < 1536 * H_; i += stride) bw1[i] = __float2bfloat16(wih1[i]);
}

// acc layout: 0,1=r(jh0,1)  2,3=z  4,5=gi_n  6,7=gh_n
template<int KP, int NG>
__device__ __forceinline__ void chunk6(const __hip_bfloat16* wl, int l15, int kg, int kc,
                                       short8 bf, f32x4* acc) {
    #pragma unroll
    for (int g = 0; g < 3; ++g) {
        const int ai = (g == 2) ? NG : g * 2;
        #pragma unroll
        for (int jh = 0; jh < 2; ++jh) {
            short8 wf = *(const short8*)&wl[(size_t)(g * 32 + jh * 16 + l15) * KP + kc * 32 + kg];
            acc[ai + jh] = __builtin_amdgcn_mfma_f32_16x16x32_bf16(wf, bf, acc[ai + jh], 0, 0, 0);
        }
    }
}

// gi1 variant: weights streamed from global bf16 (L2-cached, read-only)
__device__ __forceinline__ void chunk6g(const __hip_bfloat16* wg, int l15, int kg, int kc,
                                        short8 bf, f32x4* acc, int jb) {
    #pragma unroll
    for (int g = 0; g < 3; ++g) {
        const int ai = (g == 2) ? 4 : g * 2;
        #pragma unroll
        for (int jh = 0; jh < 2; ++jh) {
            const __hip_bfloat16* p = wg + (size_t)(g * H_ + jb + l15 * 2 + jh) * H_ + kc * 32 + kg;
            short8 wf = *(const short8*)p;
            acc[ai + jh] = __builtin_amdgcn_mfma_f32_16x16x32_bf16(wf, bf, acc[ai + jh], 0, 0, 0);
        }
    }
}

// 4-phase counted-vmcnt gather of 16 x 1KB tiles; CH(c, V) consumes chunk c
#define GATHER16(TB, CH) do { \
    short8 A0,A1,A2,A3,B0,B1,B2,B3; \
    A0=ld16sc((TB)); A1=ld16sc((TB)+512); A2=ld16sc((TB)+1024); A3=ld16sc((TB)+1536); \
    B0=ld16sc((TB)+2048); B1=ld16sc((TB)+2560); B2=ld16sc((TB)+3072); B3=ld16sc((TB)+3584); \
    VMWAIT(4); \
    CH(0,A0); CH(1,A1); CH(2,A2); CH(3,A3); \
    A0=ld16sc((TB)+4096); A1=ld16sc((TB)+4608); A2=ld16sc((TB)+5120); A3=ld16sc((TB)+5632); \
    VMWAIT(4); \
    CH(4,B0); CH(5,B1); CH(6,B2); CH(7,B3); \
    B0=ld16sc((TB)+6144); B1=ld16sc((TB)+6656); B2=ld16sc((TB)+7168); B3=ld16sc((TB)+7680); \
    VMWAIT(4); \
    CH(8,A0); CH(9,A1); CH(10,A2); CH(11,A3); \
    VMWAIT(0); \
    CH(12,B0); CH(13,B1); CH(14,B2); CH(15,B3); \
} while (0)

#define CHH(c, V) { short8 bfv = z ? zed : (V); chunk6<KP_, 6>(wlds, l15, kg, (c), bfv, acc); }
#define CHG(c, V) { chunk6g(bw1, l15, kg, (c), (V), acc, jb); }

// STAGE 0 = layer0 (gi0 local from x + gh0), STAGE 1 = layer1 (gi1 from h0 gather + gh1)
// 64 blocks per stage: bt = (bid>>4)&3 (128 rows), jp = bid&15 (32 j of all 3 gates).
// 8 waves = 8 disjoint 16-row groups. j-mapping permuted: frag (jh,l15) -> j = jb + l15*2 + jh
// so each lane's 8 outputs are j = jb + q*8 + 0..7 (contiguous).
template<int STAGE>
__device__ void run_stage(
    const float* __restrict__ x, const int* __restrict__ is_init,
    const float* __restrict__ h_in,
    const float* __restrict__ Wi_f32, const float* __restrict__ Wh_f32,
    const float* __restrict__ bi, const float* __restrict__ bh,
    const __hip_bfloat16* __restrict__ bw1,
    __hip_bfloat16* __restrict__ h0r, __hip_bfloat16* __restrict__ h1r,
    int* __restrict__ fh0, int* __restrict__ fh1,
    float* __restrict__ out, __hip_bfloat16* wsh,
    int bt, int jp)
{
    __hip_bfloat16* wlds  = wsh;                 // whh (96 x KP_)
    __hip_bfloat16* wlds2 = wsh + 96 * KP_;      // wih0 (96 x KP0_), STAGE 0 only

    const int rb = bt * 128;
    const int jb = jp * 32;
    const int tid = threadIdx.x;
    const int lane = tid & 63;
    const int w = tid >> 6;
    const int l15 = lane & 15;
    const int q = lane >> 4;
    const int kg = q * 8;
    const int bw = rb + w * 16 + l15;
    const int b16 = bt * 8 + w;

    // ---- stage whh into LDS (permuted rows), once ----
    for (int idx = tid; idx < 96 * 64; idx += 512) {
        int gr = idx >> 6, c8 = idx & 63;
        int n = gr & 31;
        int grow = (gr >> 5) * H_ + jb + (n & 15) * 2 + (n >> 4);
        const float* p = Wh_f32 + (size_t)grow * H_ + c8 * 8;
        *(short8*)&wlds[(size_t)gr * KP_ + c8 * 8] = cvt8v(*(const f32x4*)p, *(const f32x4*)(p + 4));
    }
    if (STAGE == 0) {
        for (int idx = tid; idx < 96 * 32; idx += 512) {
            int gr = idx >> 5, c8 = idx & 31;
            int n = gr & 31;
            int grow = (gr >> 5) * H_ + jb + (n & 15) * 2 + (n >> 4);
            const float* p = Wi_f32 + (size_t)grow * DIN_ + c8 * 8;
            *(short8*)&wlds2[(size_t)gr * KP0_ + c8 * 8] = cvt8v(*(const f32x4*)p, *(const f32x4*)(p + 4));
        }
    }

    // ---- per-lane constants (8 consecutive j) ----
    float bRe[8], bZe[8], bIe[8], bHe[8], hp8[8];
    #pragma unroll
    for (int e = 0; e < 8; ++e) {
        int j = jb + q * 8 + e;
        bRe[e] = bi[j] + bh[j];
        bZe[e] = bi[H_ + j] + bh[H_ + j];
        bIe[e] = bi[2 * H_ + j];
        bHe[e] = bh[2 * H_ + j];
        hp8[e] = h_in[(size_t)bw * 2 * H_ + STAGE * H_ + j];
    }
    __syncthreads();

    const short8 zed = {0, 0, 0, 0, 0, 0, 0, 0};

    for (int t = 0; t < T_; ++t) {
        f32x4 acc[8];
        #pragma unroll
        for (int i = 0; i < 8; ++i) acc[i] = f32x4{0.f, 0.f, 0.f, 0.f};

        int zi = is_init[(size_t)bw * T_ + t];
        asm volatile("" : "+v"(zi));           // materialize before asm region
        const bool z = zi != 0;

        if (STAGE == 0) {
            // ---- phase A: gi0 = x @ wih0^T (local, no dependency) ----
            const float* xr = x + ((size_t)bw * T_ + t) * DIN_;
            #pragma unroll
            for (int kc = 0; kc < 8; ++kc) {
                short8 bf = cvt8v(*(const f32x4*)(xr + kc * 32 + kg),
                                  *(const f32x4*)(xr + kc * 32 + kg + 4));
                chunk6<KP0_, 4>(wlds2, l15, kg, kc, bf, acc);
            }
            // ---- wait: siblings done t-1; R1 consumed h0[t-4] (ring overwrite) ----
            if (w == 0) {
                const int* a = nullptr;
                if (lane < 16)                      { if (t > 0)  a = &fh0[((t - 1) * 4 + bt) * 16 + lane]; }
                else if (lane >= 32 && lane < 48)   { if (t >= 4) a = &fh1[((t - 4) * 4 + bt) * 16 + (lane - 32)]; }
                if (a)
                    while (__hip_atomic_load(a, __ATOMIC_RELAXED, __HIP_MEMORY_SCOPE_AGENT) == 0)
                        __builtin_amdgcn_s_sleep(1);
            }
            __syncthreads();
            // ---- gh0 ----
            if (t == 0) {
                const float* hr = h_in + (size_t)bw * 2 * H_;
                #pragma unroll
                for (int kc = 0; kc < 16; ++kc) {
                    short8 bf = z ? zed : cvt8v(*(const f32x4*)(hr + kc * 32 + kg),
                                                *(const f32x4*)(hr + kc * 32 + kg + 4));
                    chunk6<KP_, 6>(wlds, l15, kg, kc, bf, acc);
                }
            } else {
                const __hip_bfloat16* tb = h0r + (((size_t)((t - 1) & 3) * 32 + b16) * 16) * 512 + lane * 8;
                GATHER16(tb, CHH);
            }
        } else {
            // ---- wait: siblings done t-1 (gh1 operand) ----
            if (w == 0 && t > 0 && lane >= 16 && lane < 32) {
                const int* a = &fh1[((t - 1) * 4 + bt) * 16 + (lane - 16)];
                while (__hip_atomic_load(a, __ATOMIC_RELAXED, __HIP_MEMORY_SCOPE_AGENT) == 0)
                    __builtin_amdgcn_s_sleep(1);
            }
            __syncthreads();
            // ---- gh1 ----
            if (t == 0) {
                const float* hr = h_in + (size_t)bw * 2 * H_ + H_;
                #pragma unroll
                for (int kc = 0; kc < 16; ++kc) {
                    short8 bf = z ? zed : cvt8v(*(const f32x4*)(hr + kc * 32 + kg),
                                                *(const f32x4*)(hr + kc * 32 + kg + 4));
                    chunk6<KP_, 6>(wlds, l15, kg, kc, bf, acc);
                }
            } else {
                const __hip_bfloat16* tb = h1r + (((size_t)((t - 1) & 3) * 32 + b16) * 16) * 512 + lane * 8;
                GATHER16(tb, CHH);
            }
            // ---- wait: h0[t] ready (all 16 jp producers) ----
            if (w == 0 && lane < 16) {
                const int* a = &fh0[(t * 4 + bt) * 16 + lane];
                while (__hip_atomic_load(a, __ATOMIC_RELAXED, __HIP_MEMORY_SCOPE_AGENT) == 0)
                    __builtin_amdgcn_s_sleep(1);
            }
            __syncthreads();
            // ---- gi1 = h0[t] @ wih1^T (weights streamed from L2) ----
            {
                const __hip_bfloat16* tb = h0r + (((size_t)(t & 3) * 32 + b16) * 16) * 512 + lane * 8;
                GATHER16(tb, CHG);
            }
        }

        // ---- fused gate epilogue ----
        float hv8[8];
        #pragma unroll
        for (int e = 0; e < 8; ++e) {
            const int jh = e & 1, r = e >> 1;
            const float rr = sigm(acc[jh][r] + bRe[e]);
            const float zz = sigm(acc[2 + jh][r] + bZe[e]);
            const float nn = tanhf(acc[4 + jh][r] + bIe[e] + rr * (acc[6 + jh][r] + bHe[e]));
            const float hprev = z ? 0.0f : hp8[e];
            hv8[e] = (1.0f - zz) * nn + zz * hprev;
            hp8[e] = hv8[e];
        }
        union { unsigned short us[8]; unsigned long long u[2]; } pk;
        #pragma unroll
        for (int e = 0; e < 8; ++e) pk.us[e] = f2bf(hv8[e]);
        __hip_bfloat16* ring = STAGE ? h1r : h0r;
        __hip_bfloat16* hw = ring + (((size_t)(t & 3) * 32 + b16) * 16 + jp) * 512 + lane * 8;
        st8sc(hw, pk.u[0]);
        st8sc(hw + 4, pk.u[1]);

        const int jo = jb + q * 8;
        if (STAGE == 1) {
            f32x4 o0 = {hv8[0], hv8[1], hv8[2], hv8[3]};
            f32x4 o1 = {hv8[4], hv8[5], hv8[6], hv8[7]};
            *(f32x4*)&out[((size_t)bw * T_ + t) * H_ + jo]     = o0;
            *(f32x4*)&out[((size_t)bw * T_ + t) * H_ + jo + 4] = o1;
            if (t == T_ - 1) {
                *(f32x4*)&out[OUT_MAIN + (size_t)bw * 2 * H_ + H_ + jo]     = o0;
                *(f32x4*)&out[OUT_MAIN + (size_t)bw * 2 * H_ + H_ + jo + 4] = o1;
            }
        } else if (t == T_ - 1) {
            f32x4 o0 = {hv8[0], hv8[1], hv8[2], hv8[3]};
            f32x4 o1 = {hv8[4], hv8[5], hv8[6], hv8[7]};
            *(f32x4*)&out[OUT_MAIN + (size_t)bw * 2 * H_ + jo]     = o0;
            *(f32x4*)&out[OUT_MAIN + (size_t)bw * 2 * H_ + jo + 4] = o1;
        }

        __syncthreads();   // drains all waves' stores (vmcnt0) before publish
        if (tid == 0) {
            int* f = (STAGE ? fh1 : fh0) + (t * 4 + bt) * 16 + jp;
            __hip_atomic_store(f, 1, __ATOMIC_RELAXED, __HIP_MEMORY_SCOPE_AGENT);
        }
    }
}

__global__ __launch_bounds__(512) void gru_pipe(
    const float* __restrict__ x, const int* __restrict__ is_init,
    const float* __restrict__ h_in,
    const float* __restrict__ wih0, const float* __restrict__ whh0,
    const float* __restrict__ bih0, const float* __restrict__ bhh0,
    const float* __restrict__ whh1,
    const float* __restrict__ bih1, const float* __restrict__ bhh1,
    char* __restrict__ ws, float* __restrict__ out)
{
    __shared__ __hip_bfloat16 wsh[96 * KP_ + 96 * KP0_];   // 150528 B

    __hip_bfloat16* h0r = (__hip_bfloat16*)ws;
    __hip_bfloat16* h1r = (__hip_bfloat16*)(ws + OFF_H1);
    __hip_bfloat16* bw1 = (__hip_bfloat16*)(ws + OFF_W1);
    int* flg = (int*)(ws + OFF_FLG);
    int* fh0 = flg;
    int* fh1 = flg + 8192;

    const int bid = blockIdx.x;
    const int stage = bid >> 6;
    const int bt = (bid >> 4) & 3;
    const int jp = bid & 15;

    if (stage == 0)
        run_stage<0>(x, is_init, h_in, wih0, whh0, bih0, bhh0, bw1,
                     h0r, h1r, fh0, fh1, out, wsh, bt, jp);
    else
        run_stage<1>(x, is_init, h_in, nullptr, whh1, bih1, bhh1, bw1,
                     h0r, h1r, fh0, fh1, out, wsh, bt, jp);
}

extern "C" void kernel_launch(void* const* d_in, const int* in_sizes, int n_in,
                              void* d_out, int out_size, void* d_ws, size_t ws_size,
                              hipStream_t stream) {
    (void)in_sizes; (void)n_in; (void)out_size; (void)ws_size;
    const float* x    = (const float*)d_in[0];
    const int*   isin = (const int*)d_in[1];
    const float* h_in = (const float*)d_in[2];
    const float* wih0 = (const float*)d_in[3];
    const float* whh0 = (const float*)d_in[4];
    const float* bih0 = (const float*)d_in[5];
    const float* bhh0 = (const float*)d_in[6];
    const float* wih1 = (const float*)d_in[7];
    const float* whh1 = (const float*)d_in[8];
    const float* bih1 = (const float*)d_in[9];
    const float* bhh1 = (const float*)d_in[10];
    float* out = (float*)d_out;
    char* ws = (char*)d_ws;

    prep_kernel<<<dim3(256), dim3(256), 0, stream>>>(
        wih1, (__hip_bfloat16*)(ws + OFF_W1), (int*)(ws + OFF_FLG));

    gru_pipe<<<dim3(128), dim3(512), 0, stream>>>(
        x, isin, h_in, wih0, whh0, bih0, bhh0, whh1, bih1, bhh1, ws, out);
}